// Round 1
// baseline (612.357 us; speedup 1.0000x reference)
//
#include <hip/hip_runtime.h>

// ---------------- problem dims ----------------
#define NB    8
#define DIMC  384
#define NSP   4096
#define HEADS 8
#define KDim  32
#define DDim  64
#define OCQKV 1024   // 256 q + 256 k + 512 v channels

// ---------------- GEMM tiling ----------------
#define BM 128
#define BN 128
#define BK 8

// ws layout (float offsets):
//   Wqkv [1024*384]        @ 0
//   Wpf  [384*512]         @ 393216
//   bqkv [1024]            @ 589824
//   ctx  [64*32*64]        @ 590848
//   part [8*64*32*64]      @ 721920
//   qkv  [8*1024*4096]     @ 1770496   (v-region reused for relu(attended))
// total = 35,324,928 floats = 141.3 MB

// ---------------- fold BN scale into weights ----------------
__global__ __launch_bounds__(256) void fold_weights_k(
    const float* __restrict__ Wq, const float* __restrict__ sq, const float* __restrict__ bq,
    const float* __restrict__ Wk, const float* __restrict__ sk, const float* __restrict__ bk,
    const float* __restrict__ Wv, const float* __restrict__ sv, const float* __restrict__ bv,
    const float* __restrict__ Wp, const float* __restrict__ sp,
    float* __restrict__ Wqkv, float* __restrict__ Wpf, float* __restrict__ bqkv)
{
    int i = blockIdx.x * 256 + threadIdx.x;
    const int nqkv = OCQKV * DIMC;       // 393216
    const int nprj = DIMC * 512;         // 196608
    if (i < nqkv) {
        int o = i / DIMC, c = i - o * DIMC;
        float w, s;
        if (o < 256)      { w = Wq[o * DIMC + c];         s = sq[o]; }
        else if (o < 512) { w = Wk[(o - 256) * DIMC + c]; s = sk[o - 256]; }
        else              { w = Wv[(o - 512) * DIMC + c]; s = sv[o - 512]; }
        Wqkv[i] = w * s;
    } else if (i < nqkv + nprj) {
        int j = i - nqkv;
        int o = j >> 9;                  // /512
        Wpf[j] = Wp[j] * sp[o];
    } else if (i < nqkv + nprj + OCQKV) {
        int o = i - nqkv - nprj;
        float bb;
        if (o < 256) bb = bq[o]; else if (o < 512) bb = bk[o - 256]; else bb = bv[o - 512];
        bqkv[o] = bb;
    }
}

// ---------------- generic f32 GEMM + bias: Y[b,m,n] = sum_c W[m,c]*X[b,c,n] + bias[m] ----------------
__global__ __launch_bounds__(256) void gemm_bias_k(
    const float* __restrict__ W,    // [M][K] row-major
    const float* __restrict__ bias, // [M]
    const float* __restrict__ X,    // X + b*xbs + c*NSP + n
    float* __restrict__ Y,          // Y + b*ybs + m*NSP + n
    int K, long xbs, long ybs)
{
    __shared__ float As[BK][BM + 4];
    __shared__ float Bs[BK][BN + 4];
    const int tid = threadIdx.x;
    const int b  = blockIdx.z;
    const int m0 = blockIdx.y * BM;
    const int n0 = blockIdx.x * BN;
    const int tx = tid & 15, ty = tid >> 4;

    const float* Xb = X + (long)b * xbs;
    float acc[8][8];
    #pragma unroll
    for (int u = 0; u < 8; ++u)
        #pragma unroll
        for (int v = 0; v < 8; ++v) acc[u][v] = 0.f;

    const int ai = tid >> 1;          // A row 0..127
    const int aj = (tid & 1) * 4;     // A col 0 or 4
    const int bi = (tid & 31) * 4;    // B col
    const int bj = tid >> 5;          // B row 0..7

    for (int k0 = 0; k0 < K; k0 += BK) {
        float4 av = *reinterpret_cast<const float4*>(&W[(long)(m0 + ai) * K + k0 + aj]);
        float4 bv = *reinterpret_cast<const float4*>(&Xb[(long)(k0 + bj) * NSP + n0 + bi]);
        As[aj + 0][ai] = av.x; As[aj + 1][ai] = av.y;
        As[aj + 2][ai] = av.z; As[aj + 3][ai] = av.w;
        *reinterpret_cast<float4*>(&Bs[bj][bi]) = bv;
        __syncthreads();
        #pragma unroll
        for (int k = 0; k < BK; ++k) {
            float4 a0 = *reinterpret_cast<const float4*>(&As[k][ty * 4]);
            float4 a1 = *reinterpret_cast<const float4*>(&As[k][64 + ty * 4]);
            float4 b0 = *reinterpret_cast<const float4*>(&Bs[k][tx * 4]);
            float4 b1 = *reinterpret_cast<const float4*>(&Bs[k][64 + tx * 4]);
            float aa[8] = {a0.x, a0.y, a0.z, a0.w, a1.x, a1.y, a1.z, a1.w};
            float bb[8] = {b0.x, b0.y, b0.z, b0.w, b1.x, b1.y, b1.z, b1.w};
            #pragma unroll
            for (int u = 0; u < 8; ++u)
                #pragma unroll
                for (int v = 0; v < 8; ++v)
                    acc[u][v] = fmaf(aa[u], bb[v], acc[u][v]);
        }
        __syncthreads();
    }
    #pragma unroll
    for (int u = 0; u < 8; ++u) {
        int m = m0 + ((u < 4) ? (ty * 4 + u) : (64 + ty * 4 + (u - 4)));
        float bm = bias[m];
        float4 o0 = make_float4(acc[u][0] + bm, acc[u][1] + bm, acc[u][2] + bm, acc[u][3] + bm);
        float4 o1 = make_float4(acc[u][4] + bm, acc[u][5] + bm, acc[u][6] + bm, acc[u][7] + bm);
        float* yrow = Y + (long)b * ybs + (long)m * NSP + n0;
        *reinterpret_cast<float4*>(&yrow[tx * 4])      = o0;
        *reinterpret_cast<float4*>(&yrow[64 + tx * 4]) = o1;
    }
}

// ---------------- key softmax over spatial N (in place on k region) ----------------
__global__ __launch_bounds__(256) void key_softmax_k(float* __restrict__ qkv)
{
    __shared__ float red[256];
    int r = blockIdx.x;               // 0..2047
    int b = r >> 8, ch = r & 255;
    float* row = qkv + (long)b * OCQKV * NSP + (long)(256 + ch) * NSP;
    int tid = threadIdx.x;
    float v[16];
    float mx = -1e30f;
    #pragma unroll
    for (int i = 0; i < 16; ++i) { v[i] = row[tid + i * 256]; mx = fmaxf(mx, v[i]); }
    red[tid] = mx; __syncthreads();
    for (int s = 128; s > 0; s >>= 1) {
        if (tid < s) red[tid] = fmaxf(red[tid], red[tid + s]);
        __syncthreads();
    }
    mx = red[0]; __syncthreads();
    float sum = 0.f;
    #pragma unroll
    for (int i = 0; i < 16; ++i) { v[i] = __expf(v[i] - mx); sum += v[i]; }
    red[tid] = sum; __syncthreads();
    for (int s = 128; s > 0; s >>= 1) {
        if (tid < s) red[tid] += red[tid + s];
        __syncthreads();
    }
    float inv = 1.f / red[0];
    #pragma unroll
    for (int i = 0; i < 16; ++i) row[tid + i * 256] = v[i] * inv;
}

// ---------------- query softmax over kd (32 channels within head, in place) ----------------
__global__ __launch_bounds__(256) void query_softmax_k(float* __restrict__ qkv)
{
    long g = (long)blockIdx.x * 256 + threadIdx.x;    // < B*HEADS*N = 262144
    int n  = (int)(g & (NSP - 1));
    int bh = (int)(g >> 12);
    int b = bh >> 3, h = bh & 7;
    float* base = qkv + (long)b * OCQKV * NSP + (long)(h * KDim) * NSP + n;
    float v[32]; float mx = -1e30f;
    #pragma unroll
    for (int i = 0; i < 32; ++i) { v[i] = base[(long)i * NSP]; mx = fmaxf(mx, v[i]); }
    float s = 0.f;
    #pragma unroll
    for (int i = 0; i < 32; ++i) { v[i] = __expf(v[i] - mx); s += v[i]; }
    float inv = 1.f / s;
    #pragma unroll
    for (int i = 0; i < 32; ++i) base[(long)i * NSP] = v[i] * inv;
}

// ---------------- context partials: part[chunk][bh][kd][d] = sum_{n in chunk} ksm*v ----------------
#define CCHUNK 512
__global__ __launch_bounds__(256) void context_k(const float* __restrict__ qkv, float* __restrict__ part)
{
    __shared__ float ks[KDim][65];
    __shared__ float vs[DDim][65];
    int bh = blockIdx.y;       // 0..63
    int chunk = blockIdx.x;    // 0..7
    int b = bh >> 3, h = bh & 7;
    int tid = threadIdx.x;
    const float* kbase = qkv + (long)b * OCQKV * NSP + (long)(256 + h * KDim) * NSP;
    const float* vbase = qkv + (long)b * OCQKV * NSP + (long)(512 + h * DDim) * NSP;
    int kd0 = (tid >> 4) * 2;
    int d0  = (tid & 15) * 4;
    float acc[2][4] = {{0.f,0.f,0.f,0.f},{0.f,0.f,0.f,0.f}};
    for (int n0 = chunk * CCHUNK; n0 < chunk * CCHUNK + CCHUNK; n0 += 64) {
        #pragma unroll
        for (int i = 0; i < 8; ++i) {       // 32x64 ksm tile
            int e = tid + i * 256; int rr = e >> 6, cc = e & 63;
            ks[rr][cc] = kbase[(long)rr * NSP + n0 + cc];
        }
        #pragma unroll
        for (int i = 0; i < 16; ++i) {      // 64x64 v tile
            int e = tid + i * 256; int rr = e >> 6, cc = e & 63;
            vs[rr][cc] = vbase[(long)rr * NSP + n0 + cc];
        }
        __syncthreads();
        #pragma unroll 4
        for (int n = 0; n < 64; ++n) {
            float k0v = ks[kd0][n], k1v = ks[kd0 + 1][n];
            #pragma unroll
            for (int u = 0; u < 4; ++u) {
                float vv = vs[d0 + u][n];
                acc[0][u] = fmaf(k0v, vv, acc[0][u]);
                acc[1][u] = fmaf(k1v, vv, acc[1][u]);
            }
        }
        __syncthreads();
    }
    float* p = part + ((long)chunk * 64 + bh) * (KDim * DDim);
    #pragma unroll
    for (int j = 0; j < 2; ++j)
        #pragma unroll
        for (int u = 0; u < 4; ++u)
            p[(kd0 + j) * DDim + d0 + u] = acc[j][u];
}

__global__ __launch_bounds__(256) void context_reduce_k(const float* __restrict__ part, float* __restrict__ ctx)
{
    int i = blockIdx.x * 256 + threadIdx.x;   // < 131072
    float s = 0.f;
    #pragma unroll
    for (int c = 0; c < 8; ++c) s += part[(long)c * 131072 + i];
    ctx[i] = s;
}

// ---------------- attended = ctx^T @ qsm, ReLU, written into v-region ----------------
#define ANT 256
__global__ __launch_bounds__(256) void attend_k(float* __restrict__ qkv, const float* __restrict__ ctx)
{
    __shared__ float cs[KDim][65];
    __shared__ float qs[KDim][ANT + 4];
    int bh = blockIdx.y; int b = bh >> 3, h = bh & 7;
    int nt = blockIdx.x * ANT;
    int tid = threadIdx.x;
    const float* qbase = qkv + (long)b * OCQKV * NSP + (long)(h * KDim) * NSP;
    #pragma unroll
    for (int i = 0; i < 8; ++i) {          // 32x64 ctx tile
        int e = tid + i * 256; int rr = e >> 6, cc = e & 63;
        cs[rr][cc] = ctx[(long)bh * (KDim * DDim) + rr * DDim + cc];
    }
    #pragma unroll
    for (int i = 0; i < 32; ++i) {         // 32x256 qsm tile
        int e = tid + i * 256; int rr = e >> 8, cc = e & 255;
        qs[rr][cc] = qbase[(long)rr * NSP + nt + cc];
    }
    __syncthreads();
    int dg = tid & 15, ng = tid >> 4;
    int d0 = dg * 4, n0 = ng * 16;
    float acc[4][16];
    #pragma unroll
    for (int u = 0; u < 4; ++u)
        #pragma unroll
        for (int w = 0; w < 16; ++w) acc[u][w] = 0.f;
    #pragma unroll
    for (int kd = 0; kd < KDim; ++kd) {
        float c4[4];
        #pragma unroll
        for (int u = 0; u < 4; ++u) c4[u] = cs[kd][d0 + u];
        #pragma unroll
        for (int w = 0; w < 16; ++w) {
            float qv = qs[kd][n0 + w];
            #pragma unroll
            for (int u = 0; u < 4; ++u) acc[u][w] = fmaf(c4[u], qv, acc[u][w]);
        }
    }
    float* abase = qkv + (long)b * OCQKV * NSP + (long)(512 + h * DDim) * NSP;
    #pragma unroll
    for (int u = 0; u < 4; ++u) {
        float* rowp = abase + (long)(d0 + u) * NSP + nt + n0;
        #pragma unroll
        for (int w = 0; w < 16; w += 4) {
            float4 o = make_float4(fmaxf(acc[u][w], 0.f),  fmaxf(acc[u][w + 1], 0.f),
                                   fmaxf(acc[u][w + 2], 0.f), fmaxf(acc[u][w + 3], 0.f));
            *reinterpret_cast<float4*>(&rowp[w]) = o;
        }
    }
}

// ---------------- launch ----------------
extern "C" void kernel_launch(void* const* d_in, const int* in_sizes, int n_in,
                              void* d_out, int out_size, void* d_ws, size_t ws_size,
                              hipStream_t stream) {
    (void)in_sizes; (void)n_in; (void)out_size; (void)ws_size;
    const float* x  = (const float*)d_in[0];
    const float* Wq = (const float*)d_in[1];
    const float* sq = (const float*)d_in[2];
    const float* bq = (const float*)d_in[3];
    const float* Wk = (const float*)d_in[4];
    const float* sk = (const float*)d_in[5];
    const float* bk = (const float*)d_in[6];
    const float* Wv = (const float*)d_in[7];
    const float* sv = (const float*)d_in[8];
    const float* bv = (const float*)d_in[9];
    const float* Wp = (const float*)d_in[10];
    const float* sp = (const float*)d_in[11];
    const float* bp = (const float*)d_in[12];
    float* out = (float*)d_out;

    float* ws   = (float*)d_ws;
    float* Wqkv = ws;                 // 393216
    float* Wpf  = ws + 393216;        // 196608
    float* bqkv = ws + 589824;        // 1024
    float* ctx  = ws + 590848;        // 131072
    float* part = ws + 721920;        // 1048576
    float* qkv  = ws + 1770496;       // 33554432

    fold_weights_k<<<2312, 256, 0, stream>>>(Wq, sq, bq, Wk, sk, bk, Wv, sv, bv, Wp, sp,
                                             Wqkv, Wpf, bqkv);
    // QKV projection: [1024 x 384] @ x[b] -> qkv[b]
    gemm_bias_k<<<dim3(NSP / BN, OCQKV / BM, NB), 256, 0, stream>>>(
        Wqkv, bqkv, x, qkv, DIMC, (long)DIMC * NSP, (long)OCQKV * NSP);
    key_softmax_k<<<NB * 256, 256, 0, stream>>>(qkv);
    query_softmax_k<<<(NB * HEADS * NSP) / 256, 256, 0, stream>>>(qkv);
    context_k<<<dim3(8, 64), 256, 0, stream>>>(qkv, part);
    context_reduce_k<<<512, 256, 0, stream>>>(part, ctx);
    attend_k<<<dim3(NSP / ANT, 64), 256, 0, stream>>>(qkv, ctx);
    // proj: [384 x 512] @ relu(att)[b] -> out[b]
    gemm_bias_k<<<dim3(NSP / BN, DIMC / BM, NB), 256, 0, stream>>>(
        Wpf, bp, qkv + (long)512 * NSP, out, 512, (long)OCQKV * NSP, (long)DIMC * NSP);
}

// Round 2
// 137.901 us; speedup vs baseline: 4.4406x; 4.4406x over previous
//
#include <hip/hip_runtime.h>

typedef __attribute__((ext_vector_type(8))) short bf16x8;
typedef __attribute__((ext_vector_type(4))) float f32x4;
typedef __attribute__((ext_vector_type(4))) unsigned short us4;

__device__ __forceinline__ unsigned short f2bf(float f) {
    unsigned int u = __builtin_bit_cast(unsigned int, f);
    u = (u + 0x7FFFu + ((u >> 16) & 1u)) >> 16;
    return (unsigned short)u;
}
__device__ __forceinline__ float bf2f(unsigned short h) {
    return __builtin_bit_cast(float, (unsigned int)h << 16);
}

// ---------------- fold BN into weights, emit bf16 ----------------
__global__ __launch_bounds__(256) void fold_weights_k(
    const float* __restrict__ Wq, const float* __restrict__ sq, const float* __restrict__ bq,
    const float* __restrict__ Wk, const float* __restrict__ sk, const float* __restrict__ bk,
    const float* __restrict__ Wv, const float* __restrict__ sv, const float* __restrict__ bv,
    const float* __restrict__ Wp, const float* __restrict__ sp,
    unsigned short* __restrict__ Wqkv, unsigned short* __restrict__ Wpf, float* __restrict__ bqkv)
{
    int i = blockIdx.x * 256 + threadIdx.x;
    if (i < 393216) {                       // Wqkv [1024][384]
        int o = i / 384;
        float w, s;
        if (o < 256)      { w = Wq[i];                s = sq[o]; }
        else if (o < 512) { w = Wk[i - 256 * 384];    s = sk[o - 256]; }
        else              { w = Wv[i - 512 * 384];    s = sv[o - 512]; }
        Wqkv[i] = f2bf(w * s);
    } else if (i < 589824) {                // Wpf [384][512]
        int j = i - 393216;
        Wpf[j] = f2bf(Wp[j] * sp[j >> 9]);
    } else if (i < 590848) {
        int o = i - 589824;
        bqkv[o] = (o < 256) ? bq[o] : (o < 512 ? bk[o - 256] : bv[o - 512]);
    }
}

// ---------------- x [b][384][4096] f32 -> xT [b][4096][384] bf16 ----------------
__global__ __launch_bounds__(256) void transpose_x_k(const float* __restrict__ x,
                                                     unsigned short* __restrict__ xT)
{
    __shared__ unsigned short t[64][65];
    const int b = blockIdx.z, cb = blockIdx.y << 6, nb = blockIdx.x << 6;
    const float* xb = x + ((long)b * 384 + cb) * 4096 + nb;
    #pragma unroll
    for (int i = 0; i < 16; ++i) {
        int idx = i * 256 + threadIdx.x;
        int c = idx >> 6, n = idx & 63;
        t[c][n] = f2bf(xb[(long)c * 4096 + n]);
    }
    __syncthreads();
    unsigned short* o = xT + ((long)b * 4096 + nb) * 384 + cb;
    #pragma unroll
    for (int i = 0; i < 16; ++i) {
        int idx = i * 256 + threadIdx.x;
        int n = idx >> 6, c = idx & 63;
        o[(long)n * 384 + c] = t[c][n];
    }
}

// ---------------- bf16 MFMA GEMM-BT: D = A[M][K] * Bt[N][K]^T ----------------
// MODE 0: QKV. m<256 -> qT[b][n][256] bf16 (transposed, packed); else kv[b][m-256][4096] bf16.
// MODE 1: proj. f_out[b][m][4096] f32 + bias.
template<int MODE>
__global__ __launch_bounds__(256) void gemm_bt_k(
    const unsigned short* __restrict__ A,
    const unsigned short* __restrict__ Bt,
    const float* __restrict__ bias,
    unsigned short* __restrict__ q_out,
    unsigned short* __restrict__ kv_out,
    float* __restrict__ f_out,
    int K)
{
    __shared__ unsigned short As[128 * 64];
    __shared__ unsigned short Bs[128 * 64];
    const int tid = threadIdx.x;
    const int lane = tid & 63;
    const int w = tid >> 6, wr = w >> 1, wc = w & 1;
    const int li = lane & 15, g = lane >> 4;
    const int b = blockIdx.z;
    const int n0 = blockIdx.x * 128, m0 = blockIdx.y * 128;
    const unsigned short* Bb = Bt + (long)b * 4096 * K;

    f32x4 acc[4][4];
    #pragma unroll
    for (int i = 0; i < 4; ++i)
        #pragma unroll
        for (int j = 0; j < 4; ++j)
            acc[i][j] = (f32x4){0.f, 0.f, 0.f, 0.f};

    for (int k0 = 0; k0 < K; k0 += 64) {
        #pragma unroll
        for (int j = 0; j < 4; ++j) {
            int idx = j * 256 + tid;             // 0..1023 -> 16B slots
            int r = idx >> 3;                    // row 0..127
            int ls = ((idx & 7) ^ (r & 7)) * 8;  // logical elem offset (swizzled)
            __builtin_amdgcn_global_load_lds(
                (const __attribute__((address_space(1))) void*)(A + (long)(m0 + r) * K + k0 + ls),
                (__attribute__((address_space(3))) void*)(As + (size_t)idx * 8), 16, 0, 0);
            __builtin_amdgcn_global_load_lds(
                (const __attribute__((address_space(1))) void*)(Bb + (long)(n0 + r) * K + k0 + ls),
                (__attribute__((address_space(3))) void*)(Bs + (size_t)idx * 8), 16, 0, 0);
        }
        __syncthreads();
        #pragma unroll
        for (int kk = 0; kk < 2; ++kk) {
            bf16x8 av[4], bv[4];
            #pragma unroll
            for (int mf = 0; mf < 4; ++mf) {
                int row = wr * 64 + mf * 16 + li;
                int ps = ((kk * 4 + g) ^ (row & 7)) * 8;
                av[mf] = *reinterpret_cast<const bf16x8*>(As + row * 64 + ps);
            }
            #pragma unroll
            for (int nf = 0; nf < 4; ++nf) {
                int row = wc * 64 + nf * 16 + li;
                int ps = ((kk * 4 + g) ^ (row & 7)) * 8;
                bv[nf] = *reinterpret_cast<const bf16x8*>(Bs + row * 64 + ps);
            }
            #pragma unroll
            for (int mf = 0; mf < 4; ++mf)
                #pragma unroll
                for (int nf = 0; nf < 4; ++nf)
                    acc[mf][nf] = __builtin_amdgcn_mfma_f32_16x16x32_bf16(av[mf], bv[nf], acc[mf][nf], 0, 0, 0);
        }
        __syncthreads();
    }

    #pragma unroll
    for (int mf = 0; mf < 4; ++mf) {
        int m = m0 + wr * 64 + mf * 16 + g * 4;
        #pragma unroll
        for (int nf = 0; nf < 4; ++nf) {
            int n = n0 + wc * 64 + nf * 16 + li;
            f32x4 v = acc[mf][nf];
            if (MODE == 0) {
                if (m0 < 256) {
                    us4 o = { f2bf(v.x + bias[m]),     f2bf(v.y + bias[m + 1]),
                              f2bf(v.z + bias[m + 2]), f2bf(v.w + bias[m + 3]) };
                    *reinterpret_cast<us4*>(q_out + (((long)b * 4096 + n) << 8) + m) = o;
                } else {
                    #pragma unroll
                    for (int r = 0; r < 4; ++r)
                        kv_out[((long)b * 768 + (m - 256 + r)) * 4096 + n] = f2bf(v[r] + bias[m + r]);
                }
            } else {
                #pragma unroll
                for (int r = 0; r < 4; ++r)
                    f_out[((long)b * 384 + m + r) * 4096 + n] = v[r] + bias[m + r];
            }
        }
    }
}

// ---------------- key softmax over N, rows of kv[b][ch<256][4096], bf16 in/out ----------------
__global__ __launch_bounds__(256) void key_softmax_k(unsigned short* __restrict__ kv)
{
    __shared__ float red[256];
    const int row = blockIdx.x;             // 0..2047
    unsigned short* p = kv + ((long)(row >> 8) * 768 + (row & 255)) * 4096;
    const int tid = threadIdx.x;
    us4 u[4];
    float f[16];
    #pragma unroll
    for (int i = 0; i < 4; ++i) u[i] = *reinterpret_cast<const us4*>(p + tid * 16 + i * 4);
    float mx = -1e30f;
    #pragma unroll
    for (int i = 0; i < 4; ++i)
        #pragma unroll
        for (int j = 0; j < 4; ++j) { f[i * 4 + j] = bf2f(u[i][j]); mx = fmaxf(mx, f[i * 4 + j]); }
    red[tid] = mx; __syncthreads();
    for (int s = 128; s > 0; s >>= 1) { if (tid < s) red[tid] = fmaxf(red[tid], red[tid + s]); __syncthreads(); }
    mx = red[0]; __syncthreads();
    float sum = 0.f;
    #pragma unroll
    for (int i = 0; i < 16; ++i) { f[i] = __expf(f[i] - mx); sum += f[i]; }
    red[tid] = sum; __syncthreads();
    for (int s = 128; s > 0; s >>= 1) { if (tid < s) red[tid] += red[tid + s]; __syncthreads(); }
    float inv = 1.f / red[0];
    #pragma unroll
    for (int i = 0; i < 4; ++i) {
        us4 o = { f2bf(f[i * 4] * inv), f2bf(f[i * 4 + 1] * inv), f2bf(f[i * 4 + 2] * inv), f2bf(f[i * 4 + 3] * inv) };
        *reinterpret_cast<us4*>(p + tid * 16 + i * 4) = o;
    }
}

// ---------------- query softmax over 32 contiguous channels of qT, in place ----------------
__global__ __launch_bounds__(256) void query_softmax_k(unsigned short* __restrict__ qT)
{
    int gidx = blockIdx.x * 256 + threadIdx.x;   // < 262144
    int h = gidx & 7, n = (gidx >> 3) & 4095, b = gidx >> 15;
    unsigned short* p = qT + (((long)b * 4096 + n) << 8) + h * 32;
    us4 u[8];
    float f[32];
    #pragma unroll
    for (int i = 0; i < 8; ++i) u[i] = *reinterpret_cast<const us4*>(p + i * 4);
    float mx = -1e30f;
    #pragma unroll
    for (int i = 0; i < 8; ++i)
        #pragma unroll
        for (int j = 0; j < 4; ++j) { f[i * 4 + j] = bf2f(u[i][j]); mx = fmaxf(mx, f[i * 4 + j]); }
    float sum = 0.f;
    #pragma unroll
    for (int i = 0; i < 32; ++i) { f[i] = __expf(f[i] - mx); sum += f[i]; }
    float inv = 1.f / sum;
    #pragma unroll
    for (int i = 0; i < 8; ++i) {
        us4 o = { f2bf(f[i * 4] * inv), f2bf(f[i * 4 + 1] * inv), f2bf(f[i * 4 + 2] * inv), f2bf(f[i * 4 + 3] * inv) };
        *reinterpret_cast<us4*>(p + i * 4) = o;
    }
}

// ---------------- context partials: ctx[kd][d] = sum_n ksm[kd][n]*v[d][n], MFMA, reg-direct ----------------
__global__ __launch_bounds__(256) void context_k(const unsigned short* __restrict__ kv,
                                                 float* __restrict__ part)
{
    __shared__ float lds[4][2048];
    const int bh = blockIdx.y, ck = blockIdx.x;
    const int b = bh >> 3, h = bh & 7;
    const int tid = threadIdx.x, lane = tid & 63, w = tid >> 6;
    const int li = lane & 15, g = lane >> 4;
    const unsigned short* kb = kv + ((long)b * 768 + h * 32) * 4096;
    const unsigned short* vb = kv + ((long)b * 768 + 256 + h * 64) * 4096;
    f32x4 acc[2][4];
    #pragma unroll
    for (int i = 0; i < 2; ++i)
        #pragma unroll
        for (int j = 0; j < 4; ++j) acc[i][j] = (f32x4){0.f, 0.f, 0.f, 0.f};

    const int nb0 = ck * 512 + w * 128 + g * 8;
    #pragma unroll
    for (int t = 0; t < 4; ++t) {
        int nb = nb0 + t * 32;
        bf16x8 a0 = *reinterpret_cast<const bf16x8*>(kb + (long)li * 4096 + nb);
        bf16x8 a1 = *reinterpret_cast<const bf16x8*>(kb + (long)(16 + li) * 4096 + nb);
        #pragma unroll
        for (int nf = 0; nf < 4; ++nf) {
            bf16x8 bv = *reinterpret_cast<const bf16x8*>(vb + (long)(nf * 16 + li) * 4096 + nb);
            acc[0][nf] = __builtin_amdgcn_mfma_f32_16x16x32_bf16(a0, bv, acc[0][nf], 0, 0, 0);
            acc[1][nf] = __builtin_amdgcn_mfma_f32_16x16x32_bf16(a1, bv, acc[1][nf], 0, 0, 0);
        }
    }
    #pragma unroll
    for (int mf = 0; mf < 2; ++mf)
        #pragma unroll
        for (int nf = 0; nf < 4; ++nf)
            #pragma unroll
            for (int r = 0; r < 4; ++r) {
                int kd = mf * 16 + g * 4 + r, d = nf * 16 + li;
                lds[w][kd * 64 + d] = acc[mf][nf][r];
            }
    __syncthreads();
    for (int i = tid; i < 2048; i += 256)
        part[((long)ck * 64 + bh) * 2048 + i] = lds[0][i] + lds[1][i] + lds[2][i] + lds[3][i];
}

// ---------------- reduce partials -> ctxT[bh][d][kd] bf16 ----------------
__global__ __launch_bounds__(256) void ctx_reduce_k(const float* __restrict__ part,
                                                    unsigned short* __restrict__ ctxT)
{
    int t = blockIdx.x * 256 + threadIdx.x;   // < 131072
    int bh = t >> 11, i = t & 2047;
    int d = i >> 5, kd = i & 31;
    float s = 0.f;
    #pragma unroll
    for (int c = 0; c < 8; ++c) s += part[((long)c * 64 + bh) * 2048 + kd * 64 + d];
    ctxT[t] = f2bf(s);
}

// ---------------- attended^T[n][d] = sum_kd qsmT[n][kd]*ctxT[d][kd], ReLU, bf16 ----------------
__global__ __launch_bounds__(256) void attend_k(const unsigned short* __restrict__ qT,
                                                const unsigned short* __restrict__ ctxT,
                                                unsigned short* __restrict__ attT)
{
    const int bh = blockIdx.y, nc = blockIdx.x;
    const int b = bh >> 3, h = bh & 7;
    const int lane = threadIdx.x & 63, w = threadIdx.x >> 6;
    const int li = lane & 15, g = lane >> 4;
    const int n0 = nc * 256 + w * 64;
    const unsigned short* qb = qT + (((long)b * 4096 + n0) << 8) + h * 32;
    const unsigned short* cb = ctxT + (long)bh * 2048;
    bf16x8 av[4], bv[4];
    #pragma unroll
    for (int mf = 0; mf < 4; ++mf)
        av[mf] = *reinterpret_cast<const bf16x8*>(qb + ((long)(mf * 16 + li) << 8) + g * 8);
    #pragma unroll
    for (int nf = 0; nf < 4; ++nf)
        bv[nf] = *reinterpret_cast<const bf16x8*>(cb + (nf * 16 + li) * 32 + g * 8);
    f32x4 acc[4][4];
    #pragma unroll
    for (int i = 0; i < 4; ++i)
        #pragma unroll
        for (int j = 0; j < 4; ++j) acc[i][j] = (f32x4){0.f, 0.f, 0.f, 0.f};
    #pragma unroll
    for (int mf = 0; mf < 4; ++mf)
        #pragma unroll
        for (int nf = 0; nf < 4; ++nf)
            acc[mf][nf] = __builtin_amdgcn_mfma_f32_16x16x32_bf16(av[mf], bv[nf], acc[mf][nf], 0, 0, 0);
    #pragma unroll
    for (int mf = 0; mf < 4; ++mf)
        #pragma unroll
        for (int nf = 0; nf < 4; ++nf)
            #pragma unroll
            for (int r = 0; r < 4; ++r) {
                int n = n0 + mf * 16 + g * 4 + r;
                int d = nf * 16 + li;
                float xv = acc[mf][nf][r];
                xv = xv > 0.f ? xv : 0.f;
                attT[(((long)b * 4096 + n) << 9) + h * 64 + d] = f2bf(xv);
            }
}

// ---------------- launch ----------------
extern "C" void kernel_launch(void* const* d_in, const int* in_sizes, int n_in,
                              void* d_out, int out_size, void* d_ws, size_t ws_size,
                              hipStream_t stream) {
    (void)in_sizes; (void)n_in; (void)out_size; (void)ws_size;
    const float* x  = (const float*)d_in[0];
    const float* Wq = (const float*)d_in[1];
    const float* sq = (const float*)d_in[2];
    const float* bq = (const float*)d_in[3];
    const float* Wk = (const float*)d_in[4];
    const float* sk = (const float*)d_in[5];
    const float* bk = (const float*)d_in[6];
    const float* Wv = (const float*)d_in[7];
    const float* sv = (const float*)d_in[8];
    const float* bv = (const float*)d_in[9];
    const float* Wp = (const float*)d_in[10];
    const float* sp = (const float*)d_in[11];
    const float* bp = (const float*)d_in[12];
    float* out = (float*)d_out;

    char* wsb = (char*)d_ws;
    unsigned short* Wqkv = (unsigned short*)(wsb);              // 786432 B
    unsigned short* Wpf  = (unsigned short*)(wsb + 786432);     // 393216 B
    float*          bqkv = (float*)(wsb + 1179648);             // 4096 B
    unsigned short* ctxT = (unsigned short*)(wsb + 1183744);    // 262144 B
    float*          part = (float*)(wsb + 1445888);             // 4194304 B
    unsigned short* xT   = (unsigned short*)(wsb + 5640192);    // 25165824 B
    unsigned short* qT   = (unsigned short*)(wsb + 30806016);   // 16777216 B
    unsigned short* kv   = (unsigned short*)(wsb + 47583232);   // 50331648 B
    unsigned short* attT = (unsigned short*)(wsb + 97914880);   // 33554432 B -> 131.5 MB total

    fold_weights_k<<<2308, 256, 0, stream>>>(Wq, sq, bq, Wk, sk, bk, Wv, sv, bv, Wp, sp,
                                             Wqkv, Wpf, bqkv);
    transpose_x_k<<<dim3(64, 6, 8), 256, 0, stream>>>(x, xT);
    gemm_bt_k<0><<<dim3(32, 8, 8), 256, 0, stream>>>(Wqkv, xT, bqkv, qT, kv, nullptr, 384);
    key_softmax_k<<<2048, 256, 0, stream>>>(kv);
    query_softmax_k<<<1024, 256, 0, stream>>>(qT);
    context_k<<<dim3(8, 64), 256, 0, stream>>>(kv, part);
    ctx_reduce_k<<<512, 256, 0, stream>>>(part, ctxT);
    attend_k<<<dim3(16, 64), 256, 0, stream>>>(qT, ctxT, attT);
    gemm_bt_k<1><<<dim3(32, 3, 8), 256, 0, stream>>>(Wpf, attT, bp, nullptr, nullptr, out, 512);
}